// Round 16
// baseline (1223.193 us; speedup 1.0000x reference)
//
#include <hip/hip_runtime.h>
#include <stdint.h>

#define DEV __device__ __forceinline__

typedef __bf16 bf16x8 __attribute__((ext_vector_type(8)));
typedef float  f32x4  __attribute__((ext_vector_type(4)));

struct alignas(8) U16x4 { uint16_t x, y, z, w; };
struct alignas(16) U16x8 { uint16_t v[8]; };

DEV uint16_t f2bf(float f) {
  union { float f; uint32_t u; } v; v.f = f;
  uint32_t r = v.u + 0x7fffu + ((v.u >> 16) & 1u);
  return (uint16_t)(r >> 16);
}
DEV float bf2f(uint16_t u) {
  union { uint32_t u; float f; } v; v.u = ((uint32_t)u) << 16;
  return v.f;
}

DEV void gload16(const void* g, void* l) {
  __builtin_amdgcn_global_load_lds((__attribute__((address_space(1))) void*)(g),
                                   (__attribute__((address_space(3))) void*)(l),
                                   16, 0, 0);
}

// ---------------------------------------------------------------------------
// Weight transpose + f32->bf16:  in [R][C] f32  ->  out [C][R] bf16
// ---------------------------------------------------------------------------
__global__ __launch_bounds__(1024) void transpose_cvt(
    const float* __restrict__ in, uint16_t* __restrict__ out, int R, int C) {
  __shared__ float tile[32][33];
  const int tx = threadIdx.x, ty = threadIdx.y;
  const int r = blockIdx.y * 32 + ty, c = blockIdx.x * 32 + tx;
  tile[ty][tx] = in[(size_t)r * C + c];
  __syncthreads();
  const int oc = blockIdx.x * 32 + ty;
  const int orr = blockIdx.y * 32 + tx;
  out[(size_t)oc * R + orr] = f2bf(tile[tx][ty]);
}

// ---------------------------------------------------------------------------
// Slice src into modal1/modal2 token-major bf16 [16384][1024]
// ---------------------------------------------------------------------------
__global__ __launch_bounds__(256) void cvt_modal(
    const float* __restrict__ src, uint16_t* __restrict__ m1, uint16_t* __restrict__ m2) {
  const int idx = blockIdx.x * 256 + threadIdx.x;
  const int E = idx * 4;
  const int t = E >> 10, dd = E & 1023;
  const size_t s1 = ((size_t)(t >> 7) * 256 + (t & 127)) * 1024 + dd;
  float4 a = *(const float4*)&src[s1];
  float4 b = *(const float4*)&src[s1 + 131072];
  U16x4 pa{f2bf(a.x), f2bf(a.y), f2bf(a.z), f2bf(a.w)};
  U16x4 pb{f2bf(b.x), f2bf(b.y), f2bf(b.z), f2bf(b.w)};
  *(U16x4*)&m1[E] = pa;
  *(U16x4*)&m2[E] = pb;
}

// ===========================================================================
// Kernel A: gemm256 — 16 waves (4Mx4N, 64x64/wave), BK=32, 4-buf 3-deep,
// VGPR=64 + 64 acc-AGPR, 4 waves/SIMD. FFN-class (151/147 µs measured).
// STATS: fuse LN partial (sum,sumsq) accumulation into epilogue — each
// thread's 64 outputs lie in ONE batch (batch = brow/128 + (wm>>1));
// wave shfl-reduce then one atomicAdd pair per wave (32 atomics/block).
// RESID: 0 none, 1 f32 [M][1024], 2 strided src slice (soff), 3 bf16 [M][1024]
// ===========================================================================
#define TILE2(T, ST, WAITSTR)                                                   \
  {                                                                             \
    const int abase = ((T) & 3) * 8192;                                         \
    const int bbase = 32768 + ((T) & 3) * 8192;                                 \
    bf16x8 afr[4], bfr[4];                                                      \
    _Pragma("unroll") for (int n = 0; n < 4; ++n)                               \
        bfr[n] = *(const bf16x8*)&lds[bbase + boff + n * 512];                  \
    _Pragma("unroll") for (int m = 0; m < 4; ++m)                               \
        afr[m] = *(const bf16x8*)&lds[abase + aoff + m * 512];                  \
    asm volatile(WAITSTR ::: "memory");                                         \
    __builtin_amdgcn_s_barrier();                                               \
    if (ST) {                                                                   \
      const int kn = ((T) + 3) << 5;                                            \
      const int sb = (((T) + 3) & 3) * 8192;                                    \
      gload16(gA + kn, &lds[sb + wS]);                                          \
      gload16(gB + kn, &lds[32768 + sb + wS]);                                  \
    }                                                                           \
    asm volatile("s_waitcnt lgkmcnt(0)" ::: "memory");                          \
    __builtin_amdgcn_sched_barrier(0);                                          \
    __builtin_amdgcn_s_setprio(1);                                              \
    _Pragma("unroll") for (int m = 0; m < 4; ++m)                               \
        _Pragma("unroll") for (int n = 0; n < 4; ++n)                           \
        acc[m][n] = __builtin_amdgcn_mfma_f32_16x16x32_bf16(afr[m], bfr[n],     \
                                                            acc[m][n], 0, 0, 0);\
    __builtin_amdgcn_s_setprio(0);                                              \
    __builtin_amdgcn_sched_barrier(0);                                          \
  }

template <int RESID, bool RELU, bool OUTF32, bool STATS>
__global__ __launch_bounds__(1024, 1) void gemm256(
    const uint16_t* __restrict__ A, const uint16_t* __restrict__ Bt,
    const float* __restrict__ bias, const void* __restrict__ resid,
    void* __restrict__ outp, int N, int K, int nbn, int soff,
    float* __restrict__ pstats) {
  __shared__ __align__(16) uint16_t lds[65536];

  const int nwg = gridDim.x;
  const int s = (blockIdx.x & 7) * (nwg >> 3) + (blockIdx.x >> 3);
  const int bm = s / nbn, bn = s % nbn;
  const int brow = bm << 8, bcol = bn << 8;

  const int tid = threadIdx.x;
  const int w = tid >> 6, lane = tid & 63, l15 = lane & 15, lhi = lane >> 4;
  const int wm = w >> 2, wn = w & 3;

  const int srow = tid >> 2;
  const int cswz = (tid & 3) ^ ((tid >> 3) & 3);
  const uint16_t* gA = A + (size_t)(brow + srow) * K + cswz * 8;
  const uint16_t* gB = Bt + (size_t)(bcol + srow) * K + cswz * 8;
  const int wS = w * 512;

  const int p = lhi ^ ((l15 >> 1) & 3);
  const int aoff = (wm * 64 + l15) * 32 + p * 8;
  const int boff = (wn * 64 + l15) * 32 + p * 8;

  f32x4 acc[4][4];
  const f32x4 z = {0.f, 0.f, 0.f, 0.f};
#pragma unroll
  for (int m = 0; m < 4; ++m)
#pragma unroll
    for (int n = 0; n < 4; ++n) acc[m][n] = z;

  const int nt = K >> 5;

#pragma unroll
  for (int pt = 0; pt < 3; ++pt) {
    const int sb = pt * 8192, kk = pt << 5;
    gload16(gA + kk, &lds[sb + wS]);
    gload16(gB + kk, &lds[32768 + sb + wS]);
  }
  asm volatile("s_waitcnt vmcnt(4)" ::: "memory");
  __builtin_amdgcn_s_barrier();
  __builtin_amdgcn_sched_barrier(0);

  int t = 0;
  for (; t < nt - 3; ++t) TILE2(t, true, "s_waitcnt vmcnt(2)");
  TILE2(t, false, "s_waitcnt vmcnt(2)");
  ++t;
  TILE2(t, false, "s_waitcnt vmcnt(0)");
  ++t;
  TILE2(t, false, "");

  float sac = 0.f, ssac = 0.f;
#pragma unroll
  for (int n = 0; n < 4; ++n) {
    const int col = bcol + wn * 64 + n * 16 + l15;
    const float bs = bias[col];
#pragma unroll
    for (int m = 0; m < 4; ++m) {
#pragma unroll
      for (int r = 0; r < 4; ++r) {
        const int row = brow + wm * 64 + m * 16 + lhi * 4 + r;
        float v = acc[m][n][r] + bs;
        if (RELU) v = fmaxf(v, 0.f);
        if (RESID == 1) v += ((const float*)resid)[(size_t)row * 1024 + col];
        if (RESID == 2)
          v += ((const float*)resid)[((size_t)(row >> 7) * 256 + soff + (row & 127)) * 1024 + col];
        if (RESID == 3)
          v += bf2f(((const uint16_t*)resid)[(size_t)row * 1024 + col]);
        if (STATS) { sac += v; ssac += v * v; }
        if (OUTF32)
          ((float*)outp)[(size_t)row * N + col] = v;
        else
          ((uint16_t*)outp)[(size_t)row * N + col] = f2bf(v);
      }
    }
  }
  if (STATS) {
#pragma unroll
    for (int msk = 1; msk < 64; msk <<= 1) {
      sac += __shfl_xor(sac, msk, 64);
      ssac += __shfl_xor(ssac, msk, 64);
    }
    if (lane == 0) {
      const int bat = (brow >> 7) + (wm >> 1);
      atomicAdd(&pstats[bat * 2], sac);
      atomicAdd(&pstats[bat * 2 + 1], ssac);
    }
  }
}

// ===========================================================================
// Kernel B: gemm8p — 8-phase BK=64 schedule. Used on K=1024 projections.
// STATS epilogue: thread's rows span one batch (batch = brow/128 + wm).
// ===========================================================================
#define STA8(D, H, C, T) \
  gload16(Ac + (size_t)((H) * 2 + (C)) * kr64b + (size_t)(T) * 128 + aoff32, \
          &lds[(D) * 16384 + (H) * 8192 + (C) * 4096 + wS])
#define STB8(D, H, C, T) \
  gload16(Bc + (size_t)((H) * 2 + (C)) * kr64b + (size_t)(T) * 128 + boff32, \
          &lds[32768 + (D) * 16384 + (H) * 8192 + (C) * 4096 + wS])

#define PH8(Q, AB, BB, RDB, S1, S2, VMSTR)                                     \
  {                                                                            \
    if (RDB) {                                                                 \
      _Pragma("unroll") for (int n = 0; n < 4; ++n) {                          \
        bfr[n][0] = *(const bf16x8*)&lds[(BB) + bRow + n * 1024 + c0];         \
        bfr[n][1] = *(const bf16x8*)&lds[(BB) + bRow + n * 1024 + c1];         \
      }                                                                        \
    }                                                                          \
    _Pragma("unroll") for (int dm = 0; dm < 2; ++dm) {                         \
      afr[dm][0] = *(const bf16x8*)&lds[(AB) + aRow + ((Q) * 2 + dm) * 1024 + c0]; \
      afr[dm][1] = *(const bf16x8*)&lds[(AB) + aRow + ((Q) * 2 + dm) * 1024 + c1]; \
    }                                                                          \
    S1;                                                                        \
    S2;                                                                        \
    __builtin_amdgcn_s_barrier();                                              \
    asm volatile("s_waitcnt lgkmcnt(0)" ::: "memory");                         \
    __builtin_amdgcn_sched_barrier(0);                                         \
    __builtin_amdgcn_s_setprio(1);                                             \
    _Pragma("unroll") for (int dm = 0; dm < 2; ++dm)                           \
      _Pragma("unroll") for (int n = 0; n < 4; ++n) {                          \
        acc[(Q) * 2 + dm][n] = __builtin_amdgcn_mfma_f32_16x16x32_bf16(        \
            afr[dm][0], bfr[n][0], acc[(Q) * 2 + dm][n], 0, 0, 0);             \
        acc[(Q) * 2 + dm][n] = __builtin_amdgcn_mfma_f32_16x16x32_bf16(        \
            afr[dm][1], bfr[n][1], acc[(Q) * 2 + dm][n], 0, 0, 0);             \
      }                                                                        \
    __builtin_amdgcn_s_setprio(0);                                             \
    __builtin_amdgcn_sched_barrier(0);                                         \
    asm volatile(VMSTR ::: "memory");                                          \
    __builtin_amdgcn_s_barrier();                                              \
  }

#define ITER8(I, ST, VM4, VM8)                                                 \
  {                                                                            \
    const int t1 = 2 * (I) + 1, t2 = 2 * (I) + 2, t3 = 2 * (I) + 3;            \
    PH8(0, 0, 32768, 1, STA8(1, 0, 0, t1), STA8(1, 0, 1, t1), "")              \
    PH8(1, 0, 32768, 0, STA8(1, 1, 0, t1), STA8(1, 1, 1, t1), "")              \
    PH8(2, 0, 32768, 0, if (ST) STB8(0, 0, 0, t2), if (ST) STB8(0, 0, 1, t2), "") \
    PH8(3, 0, 32768, 0, if (ST) STB8(0, 1, 0, t2), if (ST) STB8(0, 1, 1, t2), VM4) \
    PH8(0, 16384, 49152, 1, if (ST) STA8(0, 0, 0, t2), if (ST) STA8(0, 0, 1, t2), "") \
    PH8(1, 16384, 49152, 0, if (ST) STA8(0, 1, 0, t2), if (ST) STA8(0, 1, 1, t2), "") \
    PH8(2, 16384, 49152, 0, if (ST) STB8(1, 0, 0, t3), if (ST) STB8(1, 0, 1, t3), "") \
    PH8(3, 16384, 49152, 0, if (ST) STB8(1, 1, 0, t3), if (ST) STB8(1, 1, 1, t3), VM8) \
  }

template <int RESID, bool RELU, bool OUTF32, bool STATS>
__global__ __launch_bounds__(512, 2) void gemm8p(
    const uint16_t* __restrict__ A, const uint16_t* __restrict__ Bt,
    const float* __restrict__ bias, const void* __restrict__ resid,
    void* __restrict__ outp, int N, int K, int nbn, int soff,
    float* __restrict__ pstats) {
  __shared__ __align__(16) uint16_t lds[65536];

  const int nwg = gridDim.x;
  const int s = (blockIdx.x & 7) * (nwg >> 3) + (blockIdx.x >> 3);
  const int bm = s / nbn, bn = s % nbn;
  const int brow = bm << 8, bcol = bn << 8;

  const int tid = threadIdx.x;
  const int w = tid >> 6, lane = tid & 63, l15 = lane & 15, lhi = lane >> 4;
  const int wm = w >> 2, wn = w & 3;

  const int cswz = (tid & 7) ^ ((tid >> 3) & 7);
  const uint32_t aoff32 =
      (uint32_t)(((size_t)(brow + (tid >> 3)) * (size_t)K + cswz * 8) * 2);
  const uint32_t boff32 =
      (uint32_t)(((size_t)(bcol + (tid >> 3)) * (size_t)K + cswz * 8) * 2);
  const char* Ac = (const char*)A;
  const char* Bc = (const char*)Bt;
  const uint32_t kr64b = (uint32_t)(64u * (uint32_t)K * 2u);
  const int wS = w * 512;

  const int c0 = (lhi ^ (l15 & 7)) * 8;
  const int c1 = c0 ^ 32;
  const int aRow = (wm * 128 + l15) * 64;
  const int bRow = (wn * 64 + l15) * 64;

  f32x4 acc[8][4];
  const f32x4 z = {0.f, 0.f, 0.f, 0.f};
#pragma unroll
  for (int m = 0; m < 8; ++m)
#pragma unroll
    for (int n = 0; n < 4; ++n) acc[m][n] = z;

  const int NI = K >> 7;

  STA8(0, 0, 0, 0); STA8(0, 0, 1, 0); STA8(0, 1, 0, 0); STA8(0, 1, 1, 0);
  STB8(0, 0, 0, 0); STB8(0, 0, 1, 0); STB8(0, 1, 0, 0); STB8(0, 1, 1, 0);
  STB8(1, 0, 0, 1); STB8(1, 0, 1, 1); STB8(1, 1, 0, 1); STB8(1, 1, 1, 1);
  asm volatile("s_waitcnt vmcnt(4)" ::: "memory");
  __builtin_amdgcn_s_barrier();
  __builtin_amdgcn_sched_barrier(0);

  {
    bf16x8 afr[2][2], bfr[4][2];
    int i = 0;
    for (; i < NI - 1; ++i)
      ITER8(i, true, "s_waitcnt vmcnt(4)", "s_waitcnt vmcnt(4)")
    ITER8(i, false, "s_waitcnt vmcnt(0)", "")
  }

  float sac = 0.f, ssac = 0.f;
#pragma unroll
  for (int n = 0; n < 4; ++n) {
    const int col = bcol + wn * 64 + n * 16 + l15;
    const float bs = bias[col];
#pragma unroll
    for (int m = 0; m < 8; ++m) {
#pragma unroll
      for (int r = 0; r < 4; ++r) {
        const int row = brow + wm * 128 + m * 16 + lhi * 4 + r;
        float v = acc[m][n][r] + bs;
        if (RELU) v = fmaxf(v, 0.f);
        if (RESID == 1) v += ((const float*)resid)[(size_t)row * 1024 + col];
        if (RESID == 2)
          v += ((const float*)resid)[((size_t)(row >> 7) * 256 + soff + (row & 127)) * 1024 + col];
        if (RESID == 3)
          v += bf2f(((const uint16_t*)resid)[(size_t)row * 1024 + col]);
        if (STATS) { sac += v; ssac += v * v; }
        if (OUTF32)
          ((float*)outp)[(size_t)row * N + col] = v;
        else
          ((uint16_t*)outp)[(size_t)row * N + col] = f2bf(v);
      }
    }
  }
  if (STATS) {
#pragma unroll
    for (int msk = 1; msk < 64; msk <<= 1) {
      sac += __shfl_xor(sac, msk, 64);
      ssac += __shfl_xor(ssac, msk, 64);
    }
    if (lane == 0) {
      const int bat = (brow >> 7) + wm;
      atomicAdd(&pstats[bat * 2], sac);
      atomicAdd(&pstats[bat * 2 + 1], ssac);
    }
  }
}

// ---------------------------------------------------------------------------
// Attention core: one block per (b,h). S=128, dh=64. Q bf16 [t][1024];
// K,V from fused KV buffer [t][2048] (K at col 0, V at col 1024).
// ---------------------------------------------------------------------------
__global__ __launch_bounds__(256) void attn_kern(
    const uint16_t* __restrict__ Q, const uint16_t* __restrict__ KV,
    uint16_t* __restrict__ O) {
  __shared__ uint16_t sm[24576];
  uint16_t* sQ = sm;
  uint16_t* sK = sm + 8192;
  uint16_t* sVt = sm + 16384;
  uint16_t* sP = sm;
  const int bh = blockIdx.x, b = bh >> 4, h = bh & 15;
  const int tid = threadIdx.x, w = tid >> 6, lane = tid & 63, l15 = lane & 15, lhi = lane >> 4;
  const size_t base = (size_t)b * 131072 + h * 64;
  const size_t bkv = (size_t)b * 262144 + h * 64;

  for (int i = 0; i < 4; ++i) {
    const int gidx = i * 256 + tid;
    const int row = gidx >> 3, co = (gidx & 7) * 8;
    *(uint4*)&sQ[row * 64 + co] = *(const uint4*)&Q[base + (size_t)row * 1024 + co];
    *(uint4*)&sK[row * 64 + co] = *(const uint4*)&KV[bkv + (size_t)row * 2048 + co];
  }
  {
    const int r = tid >> 1, cb = (tid & 1) * 32;
    for (int jj = 0; jj < 4; ++jj) {
      uint4 vv = *(const uint4*)&KV[bkv + 1024 + (size_t)r * 2048 + cb + jj * 8];
      const uint16_t* e = (const uint16_t*)&vv;
      for (int j = 0; j < 8; ++j) sVt[(cb + jj * 8 + j) * 128 + r] = e[j];
    }
  }
  __syncthreads();

  f32x4 s[2][8];
  const f32x4 z = {0.f, 0.f, 0.f, 0.f};
  for (int m = 0; m < 2; ++m)
    for (int n = 0; n < 8; ++n) s[m][n] = z;
#pragma unroll
  for (int kk = 0; kk < 2; ++kk) {
    bf16x8 aq[2];
#pragma unroll
    for (int m = 0; m < 2; ++m)
      aq[m] = *(const bf16x8*)&sQ[(w * 32 + m * 16 + l15) * 64 + kk * 32 + lhi * 8];
#pragma unroll
    for (int n = 0; n < 8; ++n) {
      bf16x8 bk = *(const bf16x8*)&sK[(n * 16 + l15) * 64 + kk * 32 + lhi * 8];
#pragma unroll
      for (int m = 0; m < 2; ++m)
        s[m][n] = __builtin_amdgcn_mfma_f32_16x16x32_bf16(aq[m], bk, s[m][n], 0, 0, 0);
    }
  }

  for (int m = 0; m < 2; ++m) {
    float mx[4], sum[4];
#pragma unroll
    for (int r = 0; r < 4; ++r) {
      float v = s[m][0][r];
      for (int n = 1; n < 8; ++n) v = fmaxf(v, s[m][n][r]);
      for (int msk = 1; msk < 16; msk <<= 1) v = fmaxf(v, __shfl_xor(v, msk, 64));
      mx[r] = v;
      sum[r] = 0.f;
    }
    for (int n = 0; n < 8; ++n)
      for (int r = 0; r < 4; ++r) {
        float e = __expf((s[m][n][r] - mx[r]) * 0.125f);
        s[m][n][r] = e;
        sum[r] += e;
      }
#pragma unroll
    for (int r = 0; r < 4; ++r) {
      float t = sum[r];
      for (int msk = 1; msk < 16; msk <<= 1) t += __shfl_xor(t, msk, 64);
      sum[r] = 1.f / t;
    }
    for (int n = 0; n < 8; ++n)
      for (int r = 0; r < 4; ++r) s[m][n][r] *= sum[r];
  }
  __syncthreads();

  for (int m = 0; m < 2; ++m)
    for (int n = 0; n < 8; ++n)
      for (int r = 0; r < 4; ++r)
        sP[(w * 32 + m * 16 + lhi * 4 + r) * 128 + n * 16 + l15] = f2bf(s[m][n][r]);
  __syncthreads();

  f32x4 o[2][4];
  for (int m = 0; m < 2; ++m)
    for (int n = 0; n < 4; ++n) o[m][n] = z;
#pragma unroll
  for (int kk = 0; kk < 4; ++kk) {
    bf16x8 ap[2];
#pragma unroll
    for (int m = 0; m < 2; ++m)
      ap[m] = *(const bf16x8*)&sP[(w * 32 + m * 16 + l15) * 128 + kk * 32 + lhi * 8];
#pragma unroll
    for (int n = 0; n < 4; ++n) {
      bf16x8 bv = *(const bf16x8*)&sVt[(n * 16 + l15) * 128 + kk * 32 + lhi * 8];
#pragma unroll
      for (int m = 0; m < 2; ++m)
        o[m][n] = __builtin_amdgcn_mfma_f32_16x16x32_bf16(ap[m], bv, o[m][n], 0, 0, 0);
    }
  }
  for (int m = 0; m < 2; ++m)
    for (int n = 0; n < 4; ++n)
      for (int r = 0; r < 4; ++r) {
        const int q = w * 32 + m * 16 + lhi * 4 + r, c = n * 16 + l15;
        O[base + (size_t)q * 1024 + c] = f2bf(o[m][n][r]);
      }
}

// ---------------------------------------------------------------------------
// LN apply: 2048 blocks (16/batch). Reads fused (sum,sumsq) per batch.
// ---------------------------------------------------------------------------
template <bool FINAL>
__global__ __launch_bounds__(256) void ln_apply(
    const uint16_t* __restrict__ x, const float* __restrict__ g,
    const float* __restrict__ bet, const float* __restrict__ pstats,
    uint16_t* __restrict__ outbf, float* __restrict__ outf) {
  const int b = blockIdx.x >> 4, c = blockIdx.x & 15, tid = threadIdx.x;
  const float S = pstats[b * 2], SS = pstats[b * 2 + 1];
  const float mu = S * (1.f / 131072.f);
  const float rs = rsqrtf(SS * (1.f / 131072.f) - mu * mu + 1e-5f);
  const size_t xb = (size_t)b * 131072;
#pragma unroll
  for (int j = 0; j < 4; ++j) {
    const int o = c * 8192 + (j * 256 + tid) * 8;
    U16x8 v = *(const U16x8*)&x[xb + o];
    float4 g0 = *(const float4*)&g[o], g1 = *(const float4*)&g[o + 4];
    float4 b0 = *(const float4*)&bet[o], b1 = *(const float4*)&bet[o + 4];
    float r[8];
    r[0] = (bf2f(v.v[0]) - mu) * rs * g0.x + b0.x;
    r[1] = (bf2f(v.v[1]) - mu) * rs * g0.y + b0.y;
    r[2] = (bf2f(v.v[2]) - mu) * rs * g0.z + b0.z;
    r[3] = (bf2f(v.v[3]) - mu) * rs * g0.w + b0.w;
    r[4] = (bf2f(v.v[4]) - mu) * rs * g1.x + b1.x;
    r[5] = (bf2f(v.v[5]) - mu) * rs * g1.y + b1.y;
    r[6] = (bf2f(v.v[6]) - mu) * rs * g1.z + b1.z;
    r[7] = (bf2f(v.v[7]) - mu) * rs * g1.w + b1.w;
    if (FINAL) {
      float4 o0{r[0], r[1], r[2], r[3]}, o1{r[4], r[5], r[6], r[7]};
      float* of = outf + (size_t)b * 262144 + o;
      *(float4*)&of[0] = o0;
      *(float4*)&of[4] = o1;
      if (outbf) {
        U16x8 u;
#pragma unroll
        for (int i = 0; i < 8; ++i) u.v[i] = f2bf(r[i]);
        *(U16x8*)&outbf[xb + o] = u;
      }
    } else {
      U16x8 u;
#pragma unroll
      for (int i = 0; i < 8; ++i) u.v[i] = f2bf(r[i]);
      *(U16x8*)&outbf[xb + o] = u;
    }
  }
}

// ---------------------------------------------------------------------------
extern "C" void kernel_launch(void* const* d_in, const int* in_sizes, int n_in,
                              void* d_out, int out_size, void* d_ws, size_t ws_size,
                              hipStream_t stream) {
  const float* src = (const float*)d_in[0];
  const float* Wq = (const float*)d_in[1];
  const float* bq = (const float*)d_in[2];
  const float* Wk = (const float*)d_in[3];
  const float* bk = (const float*)d_in[4];
  const float* Wv = (const float*)d_in[5];
  const float* bv = (const float*)d_in[6];
  const float* Wo = (const float*)d_in[7];
  const float* bo = (const float*)d_in[8];
  const float* W1 = (const float*)d_in[9];
  const float* b1 = (const float*)d_in[10];
  const float* W2 = (const float*)d_in[11];
  const float* b2 = (const float*)d_in[12];
  const float* g1 = (const float*)d_in[13];
  const float* be1 = (const float*)d_in[14];
  const float* g2 = (const float*)d_in[15];
  const float* be2 = (const float*)d_in[16];
  float* dout = (float*)d_out;
  char* ws = (char*)d_ws;

  const size_t MB = 1024 * 1024;
  uint16_t* wq_t = (uint16_t*)(ws + 0 * MB);
  uint16_t* wkv_t = (uint16_t*)(ws + 2 * MB);  // [2048][1024]: Wk^T then Wv^T
  uint16_t* wv_t = (uint16_t*)(ws + 4 * MB);   // second half of wkv_t
  uint16_t* wo_t = (uint16_t*)(ws + 6 * MB);
  uint16_t* w1_t = (uint16_t*)(ws + 8 * MB);   // [4096][1024]
  uint16_t* w2_t = (uint16_t*)(ws + 16 * MB);  // [1024][4096]
  uint16_t* m1bf = (uint16_t*)(ws + 24 * MB);
  uint16_t* mod2 = (uint16_t*)(ws + 56 * MB);
  uint16_t* QB = (uint16_t*)(ws + 88 * MB);
  uint16_t* KVB = (uint16_t*)(ws + 120 * MB);  // fused [16384][2048]
  uint16_t* ATT = (uint16_t*)(ws + 184 * MB);
  float* bkvp = (float*)(ws + 184 * MB);       // bias staging in ATT head
  uint16_t* Hbf = QB;  // FFN hidden aliases QB..ATT (88..216, all dead)
  uint16_t* mod1 = (uint16_t*)(ws + 216 * MB);
  uint16_t* XAb = (uint16_t*)(ws + 248 * MB);  // bf16 residual stream
  uint16_t* YBF = (uint16_t*)(ws + 280 * MB);  // bf16 LN1 out
  float* pstats = (float*)(ws + 312 * MB);     // 4 buffers x 128 batches x 2 f32

  // zero all 4 stat buffers (re-zeroed every call -> replay-safe)
  hipMemsetAsync(pstats, 0, 4 * 1024, stream);

  dim3 tb(32, 32);
  transpose_cvt<<<dim3(32, 32), tb, 0, stream>>>(Wq, wq_t, 1024, 1024);
  transpose_cvt<<<dim3(32, 32), tb, 0, stream>>>(Wk, wkv_t, 1024, 1024);
  transpose_cvt<<<dim3(32, 32), tb, 0, stream>>>(Wv, wv_t, 1024, 1024);
  transpose_cvt<<<dim3(32, 32), tb, 0, stream>>>(Wo, wo_t, 1024, 1024);
  transpose_cvt<<<dim3(128, 32), tb, 0, stream>>>(W1, w1_t, 1024, 4096);
  transpose_cvt<<<dim3(32, 128), tb, 0, stream>>>(W2, w2_t, 4096, 1024);
  cvt_modal<<<16384, 256, 0, stream>>>(src, mod1, mod2);

  auto phase = [&](const uint16_t* qsrc, const uint16_t* kvsrc, int soff,
                   float* out_f, uint16_t* out_bf, float* ps_mid, float* ps_fin) {
    // projections: gemm8p (measured faster at K=1024 / NI=8)
    gemm8p<0, false, false, false><<<256, 512, 0, stream>>>(
        qsrc, wq_t, bq, nullptr, QB, 1024, 1024, 4, 0, nullptr);
    hipMemcpyAsync(bkvp, bk, 4096, hipMemcpyDeviceToDevice, stream);
    hipMemcpyAsync(bkvp + 1024, bv, 4096, hipMemcpyDeviceToDevice, stream);
    gemm8p<0, false, false, false><<<512, 512, 0, stream>>>(
        kvsrc, wkv_t, bkvp, nullptr, KVB, 2048, 1024, 8, 0, nullptr);
    attn_kern<<<2048, 256, 0, stream>>>(QB, KVB, ATT);
    // out-proj + residual + fused mid-LN stats
    gemm8p<2, false, false, true><<<256, 512, 0, stream>>>(
        ATT, wo_t, bo, src, XAb, 1024, 1024, 4, soff, ps_mid);
    ln_apply<false><<<2048, 256, 0, stream>>>(XAb, g1, be1, ps_mid, YBF, nullptr);
    // FFN-class: gemm256 (measured faster; FFN2 fuses final-LN stats)
    gemm256<0, true, false, false><<<1024, 1024, 0, stream>>>(
        YBF, w1_t, b1, nullptr, Hbf, 4096, 1024, 16, 0, nullptr);
    gemm256<3, false, false, true><<<256, 1024, 0, stream>>>(
        Hbf, w2_t, b2, YBF, XAb, 1024, 4096, 4, 0, ps_fin);
    ln_apply<true><<<2048, 256, 0, stream>>>(XAb, g2, be2, ps_fin, out_bf, out_f);
  };

  phase(mod1, mod2, 0, dout, m1bf, pstats, pstats + 256);
  phase(mod2, m1bf, 128, dout + 131072, nullptr, pstats + 512, pstats + 768);

  (void)in_sizes; (void)n_in; (void)out_size; (void)ws_size;
}

// Round 17
// 1199.489 us; speedup vs baseline: 1.0198x; 1.0198x over previous
//
#include <hip/hip_runtime.h>
#include <stdint.h>

#define DEV __device__ __forceinline__

typedef __bf16 bf16x8 __attribute__((ext_vector_type(8)));
typedef float  f32x4  __attribute__((ext_vector_type(4)));

struct alignas(8) U16x4 { uint16_t x, y, z, w; };
struct alignas(16) U16x8 { uint16_t v[8]; };

DEV uint16_t f2bf(float f) {
  union { float f; uint32_t u; } v; v.f = f;
  uint32_t r = v.u + 0x7fffu + ((v.u >> 16) & 1u);
  return (uint16_t)(r >> 16);
}
DEV float bf2f(uint16_t u) {
  union { uint32_t u; float f; } v; v.u = ((uint32_t)u) << 16;
  return v.f;
}

DEV void gload16(const void* g, void* l) {
  __builtin_amdgcn_global_load_lds((__attribute__((address_space(1))) void*)(g),
                                   (__attribute__((address_space(3))) void*)(l),
                                   16, 0, 0);
}

// ---------------------------------------------------------------------------
// Weight transpose + f32->bf16:  in [R][C] f32  ->  out [C][R] bf16
// ---------------------------------------------------------------------------
__global__ __launch_bounds__(1024) void transpose_cvt(
    const float* __restrict__ in, uint16_t* __restrict__ out, int R, int C) {
  __shared__ float tile[32][33];
  const int tx = threadIdx.x, ty = threadIdx.y;
  const int r = blockIdx.y * 32 + ty, c = blockIdx.x * 32 + tx;
  tile[ty][tx] = in[(size_t)r * C + c];
  __syncthreads();
  const int oc = blockIdx.x * 32 + ty;
  const int orr = blockIdx.y * 32 + tx;
  out[(size_t)oc * R + orr] = f2bf(tile[tx][ty]);
}

// ---------------------------------------------------------------------------
// Slice src into modal1/modal2 token-major bf16 [16384][1024]
// ---------------------------------------------------------------------------
__global__ __launch_bounds__(256) void cvt_modal(
    const float* __restrict__ src, uint16_t* __restrict__ m1, uint16_t* __restrict__ m2) {
  const int idx = blockIdx.x * 256 + threadIdx.x;
  const int E = idx * 4;
  const int t = E >> 10, dd = E & 1023;
  const size_t s1 = ((size_t)(t >> 7) * 256 + (t & 127)) * 1024 + dd;
  float4 a = *(const float4*)&src[s1];
  float4 b = *(const float4*)&src[s1 + 131072];
  U16x4 pa{f2bf(a.x), f2bf(a.y), f2bf(a.z), f2bf(a.w)};
  U16x4 pb{f2bf(b.x), f2bf(b.y), f2bf(b.z), f2bf(b.w)};
  *(U16x4*)&m1[E] = pa;
  *(U16x4*)&m2[E] = pb;
}

// ---------------------------------------------------------------------------
// GEMM, 8-phase schedule (R13) with SADDR staging addressing. R14 config —
// the measured best (1204 µs total). Single template in this module to avoid
// co-compilation codegen perturbation (rule #19).
// 256x256 tile, BK=64, 8 waves (2Mx4N, 128x64/wave), 2-dbuf LDS (128 KiB).
// C[M][N] = A[M][K] @ Bt[N][K]^T + bias (+relu) (+resid)
// RESID: 0 none, 1 f32 [M][1024], 2 strided src slice (soff), 3 bf16 [M][1024]
// Requires M%256==0, N%256==0, K%128==0, grid%8==0.
// ---------------------------------------------------------------------------
#define STA8(D, H, C, T) \
  gload16(Ac + (size_t)((H) * 2 + (C)) * kr64b + (size_t)(T) * 128 + aoff32, \
          &lds[(D) * 16384 + (H) * 8192 + (C) * 4096 + wS])
#define STB8(D, H, C, T) \
  gload16(Bc + (size_t)((H) * 2 + (C)) * kr64b + (size_t)(T) * 128 + boff32, \
          &lds[32768 + (D) * 16384 + (H) * 8192 + (C) * 4096 + wS])

#define PH8(Q, AB, BB, RDB, S1, S2, VMSTR)                                     \
  {                                                                            \
    if (RDB) {                                                                 \
      _Pragma("unroll") for (int n = 0; n < 4; ++n) {                          \
        bfr[n][0] = *(const bf16x8*)&lds[(BB) + bRow + n * 1024 + c0];         \
        bfr[n][1] = *(const bf16x8*)&lds[(BB) + bRow + n * 1024 + c1];         \
      }                                                                        \
    }                                                                          \
    _Pragma("unroll") for (int dm = 0; dm < 2; ++dm) {                         \
      afr[dm][0] = *(const bf16x8*)&lds[(AB) + aRow + ((Q) * 2 + dm) * 1024 + c0]; \
      afr[dm][1] = *(const bf16x8*)&lds[(AB) + aRow + ((Q) * 2 + dm) * 1024 + c1]; \
    }                                                                          \
    S1;                                                                        \
    S2;                                                                        \
    __builtin_amdgcn_s_barrier();                                              \
    asm volatile("s_waitcnt lgkmcnt(0)" ::: "memory");                         \
    __builtin_amdgcn_sched_barrier(0);                                         \
    __builtin_amdgcn_s_setprio(1);                                             \
    _Pragma("unroll") for (int dm = 0; dm < 2; ++dm)                           \
      _Pragma("unroll") for (int n = 0; n < 4; ++n) {                          \
        acc[(Q) * 2 + dm][n] = __builtin_amdgcn_mfma_f32_16x16x32_bf16(        \
            afr[dm][0], bfr[n][0], acc[(Q) * 2 + dm][n], 0, 0, 0);             \
        acc[(Q) * 2 + dm][n] = __builtin_amdgcn_mfma_f32_16x16x32_bf16(        \
            afr[dm][1], bfr[n][1], acc[(Q) * 2 + dm][n], 0, 0, 0);             \
      }                                                                        \
    __builtin_amdgcn_s_setprio(0);                                             \
    __builtin_amdgcn_sched_barrier(0);                                         \
    asm volatile(VMSTR ::: "memory");                                          \
    __builtin_amdgcn_s_barrier();                                              \
  }

#define ITER8(I, ST, VM4, VM8)                                                 \
  {                                                                            \
    const int t1 = 2 * (I) + 1, t2 = 2 * (I) + 2, t3 = 2 * (I) + 3;            \
    PH8(0, 0, 32768, 1, STA8(1, 0, 0, t1), STA8(1, 0, 1, t1), "")              \
    PH8(1, 0, 32768, 0, STA8(1, 1, 0, t1), STA8(1, 1, 1, t1), "")              \
    PH8(2, 0, 32768, 0, if (ST) STB8(0, 0, 0, t2), if (ST) STB8(0, 0, 1, t2), "") \
    PH8(3, 0, 32768, 0, if (ST) STB8(0, 1, 0, t2), if (ST) STB8(0, 1, 1, t2), VM4) \
    PH8(0, 16384, 49152, 1, if (ST) STA8(0, 0, 0, t2), if (ST) STA8(0, 0, 1, t2), "") \
    PH8(1, 16384, 49152, 0, if (ST) STA8(0, 1, 0, t2), if (ST) STA8(0, 1, 1, t2), "") \
    PH8(2, 16384, 49152, 0, if (ST) STB8(1, 0, 0, t3), if (ST) STB8(1, 0, 1, t3), "") \
    PH8(3, 16384, 49152, 0, if (ST) STB8(1, 1, 0, t3), if (ST) STB8(1, 1, 1, t3), VM8) \
  }

template <int RESID, bool RELU, bool OUTF32>
__global__ __launch_bounds__(512, 2) void gemm8p(
    const uint16_t* __restrict__ A, const uint16_t* __restrict__ Bt,
    const float* __restrict__ bias, const void* __restrict__ resid,
    void* __restrict__ outp, int N, int K, int nbn, int soff) {
  __shared__ __align__(16) uint16_t lds[65536];

  const int nwg = gridDim.x;
  const int s = (blockIdx.x & 7) * (nwg >> 3) + (blockIdx.x >> 3);
  const int bm = s / nbn, bn = s % nbn;
  const int brow = bm << 8, bcol = bn << 8;

  const int tid = threadIdx.x;
  const int w = tid >> 6, lane = tid & 63, l15 = lane & 15, lhi = lane >> 4;
  const int wm = w >> 2, wn = w & 3;

  const int cswz = (tid & 7) ^ ((tid >> 3) & 7);
  const uint32_t aoff32 =
      (uint32_t)(((size_t)(brow + (tid >> 3)) * (size_t)K + cswz * 8) * 2);
  const uint32_t boff32 =
      (uint32_t)(((size_t)(bcol + (tid >> 3)) * (size_t)K + cswz * 8) * 2);
  const char* Ac = (const char*)A;
  const char* Bc = (const char*)Bt;
  const uint32_t kr64b = (uint32_t)(64u * (uint32_t)K * 2u);
  const int wS = w * 512;

  const int c0 = (lhi ^ (l15 & 7)) * 8;
  const int c1 = c0 ^ 32;
  const int aRow = (wm * 128 + l15) * 64;
  const int bRow = (wn * 64 + l15) * 64;

  f32x4 acc[8][4];
  const f32x4 z = {0.f, 0.f, 0.f, 0.f};
#pragma unroll
  for (int m = 0; m < 8; ++m)
#pragma unroll
    for (int n = 0; n < 4; ++n) acc[m][n] = z;

  const int NI = K >> 7;

  STA8(0, 0, 0, 0); STA8(0, 0, 1, 0); STA8(0, 1, 0, 0); STA8(0, 1, 1, 0);
  STB8(0, 0, 0, 0); STB8(0, 0, 1, 0); STB8(0, 1, 0, 0); STB8(0, 1, 1, 0);
  STB8(1, 0, 0, 1); STB8(1, 0, 1, 1); STB8(1, 1, 0, 1); STB8(1, 1, 1, 1);
  asm volatile("s_waitcnt vmcnt(4)" ::: "memory");
  __builtin_amdgcn_s_barrier();
  __builtin_amdgcn_sched_barrier(0);

  {
    bf16x8 afr[2][2], bfr[4][2];
    int i = 0;
    for (; i < NI - 1; ++i)
      ITER8(i, true, "s_waitcnt vmcnt(4)", "s_waitcnt vmcnt(4)")
    ITER8(i, false, "s_waitcnt vmcnt(0)", "")
  }

#pragma unroll
  for (int n = 0; n < 4; ++n) {
    const int col = bcol + wn * 64 + n * 16 + l15;
    const float bs = bias[col];
#pragma unroll
    for (int m = 0; m < 8; ++m) {
#pragma unroll
      for (int r = 0; r < 4; ++r) {
        const int row = brow + wm * 128 + m * 16 + lhi * 4 + r;
        float v = acc[m][n][r] + bs;
        if (RELU) v = fmaxf(v, 0.f);
        if (RESID == 1) v += ((const float*)resid)[(size_t)row * 1024 + col];
        if (RESID == 2)
          v += ((const float*)resid)[((size_t)(row >> 7) * 256 + soff + (row & 127)) * 1024 + col];
        if (RESID == 3)
          v += bf2f(((const uint16_t*)resid)[(size_t)row * 1024 + col]);
        if (OUTF32)
          ((float*)outp)[(size_t)row * N + col] = v;
        else
          ((uint16_t*)outp)[(size_t)row * N + col] = f2bf(v);
      }
    }
  }
}

// ---------------------------------------------------------------------------
// Attention core: one block per (b,h). S=128, dh=64. Q bf16 [t][1024];
// K,V from fused KV buffer [t][2048] (K at col 0, V at col 1024).
// ---------------------------------------------------------------------------
__global__ __launch_bounds__(256) void attn_kern(
    const uint16_t* __restrict__ Q, const uint16_t* __restrict__ KV,
    uint16_t* __restrict__ O) {
  __shared__ uint16_t sm[24576];
  uint16_t* sQ = sm;
  uint16_t* sK = sm + 8192;
  uint16_t* sVt = sm + 16384;
  uint16_t* sP = sm;
  const int bh = blockIdx.x, b = bh >> 4, h = bh & 15;
  const int tid = threadIdx.x, w = tid >> 6, lane = tid & 63, l15 = lane & 15, lhi = lane >> 4;
  const size_t base = (size_t)b * 131072 + h * 64;
  const size_t bkv = (size_t)b * 262144 + h * 64;

  for (int i = 0; i < 4; ++i) {
    const int gidx = i * 256 + tid;
    const int row = gidx >> 3, co = (gidx & 7) * 8;
    *(uint4*)&sQ[row * 64 + co] = *(const uint4*)&Q[base + (size_t)row * 1024 + co];
    *(uint4*)&sK[row * 64 + co] = *(const uint4*)&KV[bkv + (size_t)row * 2048 + co];
  }
  {
    const int r = tid >> 1, cb = (tid & 1) * 32;
    for (int jj = 0; jj < 4; ++jj) {
      uint4 vv = *(const uint4*)&KV[bkv + 1024 + (size_t)r * 2048 + cb + jj * 8];
      const uint16_t* e = (const uint16_t*)&vv;
      for (int j = 0; j < 8; ++j) sVt[(cb + jj * 8 + j) * 128 + r] = e[j];
    }
  }
  __syncthreads();

  f32x4 s[2][8];
  const f32x4 z = {0.f, 0.f, 0.f, 0.f};
  for (int m = 0; m < 2; ++m)
    for (int n = 0; n < 8; ++n) s[m][n] = z;
#pragma unroll
  for (int kk = 0; kk < 2; ++kk) {
    bf16x8 aq[2];
#pragma unroll
    for (int m = 0; m < 2; ++m)
      aq[m] = *(const bf16x8*)&sQ[(w * 32 + m * 16 + l15) * 64 + kk * 32 + lhi * 8];
#pragma unroll
    for (int n = 0; n < 8; ++n) {
      bf16x8 bk = *(const bf16x8*)&sK[(n * 16 + l15) * 64 + kk * 32 + lhi * 8];
#pragma unroll
      for (int m = 0; m < 2; ++m)
        s[m][n] = __builtin_amdgcn_mfma_f32_16x16x32_bf16(aq[m], bk, s[m][n], 0, 0, 0);
    }
  }

  for (int m = 0; m < 2; ++m) {
    float mx[4], sum[4];
#pragma unroll
    for (int r = 0; r < 4; ++r) {
      float v = s[m][0][r];
      for (int n = 1; n < 8; ++n) v = fmaxf(v, s[m][n][r]);
      for (int msk = 1; msk < 16; msk <<= 1) v = fmaxf(v, __shfl_xor(v, msk, 64));
      mx[r] = v;
      sum[r] = 0.f;
    }
    for (int n = 0; n < 8; ++n)
      for (int r = 0; r < 4; ++r) {
        float e = __expf((s[m][n][r] - mx[r]) * 0.125f);
        s[m][n][r] = e;
        sum[r] += e;
      }
#pragma unroll
    for (int r = 0; r < 4; ++r) {
      float t = sum[r];
      for (int msk = 1; msk < 16; msk <<= 1) t += __shfl_xor(t, msk, 64);
      sum[r] = 1.f / t;
    }
    for (int n = 0; n < 8; ++n)
      for (int r = 0; r < 4; ++r) s[m][n][r] *= sum[r];
  }
  __syncthreads();

  for (int m = 0; m < 2; ++m)
    for (int n = 0; n < 8; ++n)
      for (int r = 0; r < 4; ++r)
        sP[(w * 32 + m * 16 + lhi * 4 + r) * 128 + n * 16 + l15] = f2bf(s[m][n][r]);
  __syncthreads();

  f32x4 o[2][4];
  for (int m = 0; m < 2; ++m)
    for (int n = 0; n < 4; ++n) o[m][n] = z;
#pragma unroll
  for (int kk = 0; kk < 4; ++kk) {
    bf16x8 ap[2];
#pragma unroll
    for (int m = 0; m < 2; ++m)
      ap[m] = *(const bf16x8*)&sP[(w * 32 + m * 16 + l15) * 128 + kk * 32 + lhi * 8];
#pragma unroll
    for (int n = 0; n < 4; ++n) {
      bf16x8 bv = *(const bf16x8*)&sVt[(n * 16 + l15) * 128 + kk * 32 + lhi * 8];
#pragma unroll
      for (int m = 0; m < 2; ++m)
        o[m][n] = __builtin_amdgcn_mfma_f32_16x16x32_bf16(ap[m], bv, o[m][n], 0, 0, 0);
    }
  }
  for (int m = 0; m < 2; ++m)
    for (int n = 0; n < 4; ++n)
      for (int r = 0; r < 4; ++r) {
        const int q = w * 32 + m * 16 + lhi * 4 + r, c = n * 16 + l15;
        O[base + (size_t)q * 1024 + c] = f2bf(o[m][n][r]);
      }
}

// ---------------------------------------------------------------------------
// LN2D split. Stats: 512 blocks (4/batch); Apply: 2048 blocks (16/batch).
// ---------------------------------------------------------------------------
__global__ __launch_bounds__(256) void ln_stats(
    const uint16_t* __restrict__ x, float* __restrict__ pstats) {
  const int b = blockIdx.x >> 2, q = blockIdx.x & 3, tid = threadIdx.x;
  const uint16_t* xb = x + (size_t)b * 131072 + q * 32768;
  float s = 0.f, ss = 0.f;
  for (int i = tid; i < 4096; i += 256) {
    U16x8 v = *(const U16x8*)&xb[i * 8];
#pragma unroll
    for (int j = 0; j < 8; ++j) {
      float f = bf2f(v.v[j]);
      s += f;
      ss += f * f;
    }
  }
#pragma unroll
  for (int m = 1; m < 64; m <<= 1) {
    s += __shfl_xor(s, m, 64);
    ss += __shfl_xor(ss, m, 64);
  }
  __shared__ float red[8];
  const int w = tid >> 6;
  if ((tid & 63) == 0) { red[w] = s; red[4 + w] = ss; }
  __syncthreads();
  if (tid == 0) {
    pstats[blockIdx.x * 2] = red[0] + red[1] + red[2] + red[3];
    pstats[blockIdx.x * 2 + 1] = red[4] + red[5] + red[6] + red[7];
  }
}

template <bool FINAL>
__global__ __launch_bounds__(256) void ln_apply(
    const uint16_t* __restrict__ x, const float* __restrict__ g,
    const float* __restrict__ bet, const float* __restrict__ pstats,
    uint16_t* __restrict__ outbf, float* __restrict__ outf) {
  const int b = blockIdx.x >> 4, c = blockIdx.x & 15, tid = threadIdx.x;
  float S = 0.f, SS = 0.f;
#pragma unroll
  for (int k = 0; k < 4; ++k) {
    S += pstats[b * 8 + k * 2];
    SS += pstats[b * 8 + k * 2 + 1];
  }
  const float mu = S * (1.f / 131072.f);
  const float rs = rsqrtf(SS * (1.f / 131072.f) - mu * mu + 1e-5f);
  const size_t xb = (size_t)b * 131072;
#pragma unroll
  for (int j = 0; j < 4; ++j) {
    const int o = c * 8192 + (j * 256 + tid) * 8;
    U16x8 v = *(const U16x8*)&x[xb + o];
    float4 g0 = *(const float4*)&g[o], g1 = *(const float4*)&g[o + 4];
    float4 b0 = *(const float4*)&bet[o], b1 = *(const float4*)&bet[o + 4];
    float r[8];
    r[0] = (bf2f(v.v[0]) - mu) * rs * g0.x + b0.x;
    r[1] = (bf2f(v.v[1]) - mu) * rs * g0.y + b0.y;
    r[2] = (bf2f(v.v[2]) - mu) * rs * g0.z + b0.z;
    r[3] = (bf2f(v.v[3]) - mu) * rs * g0.w + b0.w;
    r[4] = (bf2f(v.v[4]) - mu) * rs * g1.x + b1.x;
    r[5] = (bf2f(v.v[5]) - mu) * rs * g1.y + b1.y;
    r[6] = (bf2f(v.v[6]) - mu) * rs * g1.z + b1.z;
    r[7] = (bf2f(v.v[7]) - mu) * rs * g1.w + b1.w;
    if (FINAL) {
      float4 o0{r[0], r[1], r[2], r[3]}, o1{r[4], r[5], r[6], r[7]};
      float* of = outf + (size_t)b * 262144 + o;
      *(float4*)&of[0] = o0;
      *(float4*)&of[4] = o1;
      if (outbf) {
        U16x8 u;
#pragma unroll
        for (int i = 0; i < 8; ++i) u.v[i] = f2bf(r[i]);
        *(U16x8*)&outbf[xb + o] = u;
      }
    } else {
      U16x8 u;
#pragma unroll
      for (int i = 0; i < 8; ++i) u.v[i] = f2bf(r[i]);
      *(U16x8*)&outbf[xb + o] = u;
    }
  }
}

// ---------------------------------------------------------------------------
extern "C" void kernel_launch(void* const* d_in, const int* in_sizes, int n_in,
                              void* d_out, int out_size, void* d_ws, size_t ws_size,
                              hipStream_t stream) {
  const float* src = (const float*)d_in[0];
  const float* Wq = (const float*)d_in[1];
  const float* bq = (const float*)d_in[2];
  const float* Wk = (const float*)d_in[3];
  const float* bk = (const float*)d_in[4];
  const float* Wv = (const float*)d_in[5];
  const float* bv = (const float*)d_in[6];
  const float* Wo = (const float*)d_in[7];
  const float* bo = (const float*)d_in[8];
  const float* W1 = (const float*)d_in[9];
  const float* b1 = (const float*)d_in[10];
  const float* W2 = (const float*)d_in[11];
  const float* b2 = (const float*)d_in[12];
  const float* g1 = (const float*)d_in[13];
  const float* be1 = (const float*)d_in[14];
  const float* g2 = (const float*)d_in[15];
  const float* be2 = (const float*)d_in[16];
  float* dout = (float*)d_out;
  char* ws = (char*)d_ws;

  const size_t MB = 1024 * 1024;
  uint16_t* wq_t = (uint16_t*)(ws + 0 * MB);
  uint16_t* wkv_t = (uint16_t*)(ws + 2 * MB);  // [2048][1024]: Wk^T then Wv^T
  uint16_t* wv_t = (uint16_t*)(ws + 4 * MB);   // second half of wkv_t
  uint16_t* wo_t = (uint16_t*)(ws + 6 * MB);
  uint16_t* w1_t = (uint16_t*)(ws + 8 * MB);   // [4096][1024]
  uint16_t* w2_t = (uint16_t*)(ws + 16 * MB);  // [1024][4096]
  uint16_t* m1bf = (uint16_t*)(ws + 24 * MB);
  uint16_t* mod2 = (uint16_t*)(ws + 56 * MB);
  uint16_t* QB = (uint16_t*)(ws + 88 * MB);
  uint16_t* KVB = (uint16_t*)(ws + 120 * MB);  // fused [16384][2048]
  uint16_t* ATT = (uint16_t*)(ws + 184 * MB);
  float* bkvp = (float*)(ws + 184 * MB);       // bias staging in ATT head
  uint16_t* Hbf = QB;  // FFN hidden aliases QB..ATT (88..216, all dead)
  uint16_t* mod1 = (uint16_t*)(ws + 216 * MB);
  uint16_t* XAb = (uint16_t*)(ws + 248 * MB);  // bf16 residual stream
  uint16_t* YBF = (uint16_t*)(ws + 280 * MB);  // bf16 LN1 out
  float* pstats = (float*)(ws + 312 * MB);     // 512*2 floats

  dim3 tb(32, 32);
  transpose_cvt<<<dim3(32, 32), tb, 0, stream>>>(Wq, wq_t, 1024, 1024);
  transpose_cvt<<<dim3(32, 32), tb, 0, stream>>>(Wk, wkv_t, 1024, 1024);
  transpose_cvt<<<dim3(32, 32), tb, 0, stream>>>(Wv, wv_t, 1024, 1024);
  transpose_cvt<<<dim3(32, 32), tb, 0, stream>>>(Wo, wo_t, 1024, 1024);
  transpose_cvt<<<dim3(128, 32), tb, 0, stream>>>(W1, w1_t, 1024, 4096);
  transpose_cvt<<<dim3(32, 128), tb, 0, stream>>>(W2, w2_t, 4096, 1024);
  cvt_modal<<<16384, 256, 0, stream>>>(src, mod1, mod2);

  auto phase = [&](const uint16_t* qsrc, const uint16_t* kvsrc, int soff,
                   float* out_f, uint16_t* out_bf) {
    gemm8p<0, false, false><<<256, 512, 0, stream>>>(qsrc, wq_t, bq, nullptr, QB,
                                                     1024, 1024, 4, 0);
    hipMemcpyAsync(bkvp, bk, 4096, hipMemcpyDeviceToDevice, stream);
    hipMemcpyAsync(bkvp + 1024, bv, 4096, hipMemcpyDeviceToDevice, stream);
    gemm8p<0, false, false><<<512, 512, 0, stream>>>(kvsrc, wkv_t, bkvp, nullptr, KVB,
                                                     2048, 1024, 8, 0);
    attn_kern<<<2048, 256, 0, stream>>>(QB, KVB, ATT);
    // out-proj + residual: residual == the phase's modal slice == qsrc (bf16),
    // replacing the strided f32 src read (RESID=2) — 32 MB less traffic.
    gemm8p<3, false, false><<<256, 512, 0, stream>>>(ATT, wo_t, bo, qsrc, XAb,
                                                     1024, 1024, 4, 0);
    ln_stats<<<512, 256, 0, stream>>>(XAb, pstats);
    ln_apply<false><<<2048, 256, 0, stream>>>(XAb, g1, be1, pstats, YBF, nullptr);
    gemm8p<0, true, false><<<1024, 512, 0, stream>>>(YBF, w1_t, b1, nullptr, Hbf,
                                                     4096, 1024, 16, 0);
    gemm8p<3, false, false><<<256, 512, 0, stream>>>(Hbf, w2_t, b2, YBF, XAb,
                                                     1024, 4096, 4, 0);
    ln_stats<<<512, 256, 0, stream>>>(XAb, pstats);
    ln_apply<true><<<2048, 256, 0, stream>>>(XAb, g2, be2, pstats, out_bf, out_f);
    (void)soff;
  };

  phase(mod1, mod2, 0, dout, m1bf);
  phase(mod2, m1bf, 128, dout + 131072, nullptr);

  (void)in_sizes; (void)n_in; (void)out_size; (void)ws_size;
}

// Round 18
// 1132.906 us; speedup vs baseline: 1.0797x; 1.0588x over previous
//
#include <hip/hip_runtime.h>
#include <stdint.h>

#define DEV __device__ __forceinline__

typedef __bf16 bf16x8 __attribute__((ext_vector_type(8)));
typedef float  f32x4  __attribute__((ext_vector_type(4)));

struct alignas(8) U16x4 { uint16_t x, y, z, w; };
struct alignas(16) U16x8 { uint16_t v[8]; };

DEV uint16_t f2bf(float f) {
  union { float f; uint32_t u; } v; v.f = f;
  uint32_t r = v.u + 0x7fffu + ((v.u >> 16) & 1u);
  return (uint16_t)(r >> 16);
}
DEV float bf2f(uint16_t u) {
  union { uint32_t u; float f; } v; v.u = ((uint32_t)u) << 16;
  return v.f;
}

DEV void gload16(const void* g, void* l) {
  __builtin_amdgcn_global_load_lds((__attribute__((address_space(1))) void*)(g),
                                   (__attribute__((address_space(3))) void*)(l),
                                   16, 0, 0);
}

// ---------------------------------------------------------------------------
// Weight transpose + f32->bf16:  in [R][C] f32  ->  out [C][R] bf16
// ---------------------------------------------------------------------------
__global__ __launch_bounds__(1024) void transpose_cvt(
    const float* __restrict__ in, uint16_t* __restrict__ out, int R, int C) {
  __shared__ float tile[32][33];
  const int tx = threadIdx.x, ty = threadIdx.y;
  const int r = blockIdx.y * 32 + ty, c = blockIdx.x * 32 + tx;
  tile[ty][tx] = in[(size_t)r * C + c];
  __syncthreads();
  const int oc = blockIdx.x * 32 + ty;
  const int orr = blockIdx.y * 32 + tx;
  out[(size_t)oc * R + orr] = f2bf(tile[tx][ty]);
}

// ---------------------------------------------------------------------------
// Slice src into modal1/modal2 token-major bf16 [16384][1024]
// ---------------------------------------------------------------------------
__global__ __launch_bounds__(256) void cvt_modal(
    const float* __restrict__ src, uint16_t* __restrict__ m1, uint16_t* __restrict__ m2) {
  const int idx = blockIdx.x * 256 + threadIdx.x;
  const int E = idx * 4;
  const int t = E >> 10, dd = E & 1023;
  const size_t s1 = ((size_t)(t >> 7) * 256 + (t & 127)) * 1024 + dd;
  float4 a = *(const float4*)&src[s1];
  float4 b = *(const float4*)&src[s1 + 131072];
  U16x4 pa{f2bf(a.x), f2bf(a.y), f2bf(a.z), f2bf(a.w)};
  U16x4 pb{f2bf(b.x), f2bf(b.y), f2bf(b.z), f2bf(b.w)};
  *(U16x4*)&m1[E] = pa;
  *(U16x4*)&m2[E] = pb;
}

// ---------------------------------------------------------------------------
// GEMM, 8-phase schedule (R13/R14/R17) with OPERAND-SWAPPED MFMA:
// mfma(bfr, afr, acc) computes the transposed tile, so each lane's 4 acc
// values lie in 4 CONSECUTIVE COLUMNS of one row (our_row = ...+l15,
// our_col = ...+lhi*4+r) -> epilogue packs 8-byte stores/loads:
// 32x U16x4 stores + 32x 8B resid loads + 4 float4 bias loads per thread
// (was 128 scalar 2B stores + 128 scalar 2B loads). A/B operand fragment
// layouts are identical for mfma_f32_16x16x32_bf16, so the swap is a pure
// argument swap. Schedule/staging/waits/swizzle unchanged from R17.
// C[M][N] = A[M][K] @ Bt[N][K]^T + bias (+relu) (+resid)
// RESID: 0 none, 1 f32 [M][1024], 2 strided src slice (soff), 3 bf16 [M][1024]
// Requires M%256==0, N%256==0, K%128==0, grid%8==0.
// ---------------------------------------------------------------------------
#define STA8(D, H, C, T) \
  gload16(Ac + (size_t)((H) * 2 + (C)) * kr64b + (size_t)(T) * 128 + aoff32, \
          &lds[(D) * 16384 + (H) * 8192 + (C) * 4096 + wS])
#define STB8(D, H, C, T) \
  gload16(Bc + (size_t)((H) * 2 + (C)) * kr64b + (size_t)(T) * 128 + boff32, \
          &lds[32768 + (D) * 16384 + (H) * 8192 + (C) * 4096 + wS])

#define PH8(Q, AB, BB, RDB, S1, S2, VMSTR)                                     \
  {                                                                            \
    if (RDB) {                                                                 \
      _Pragma("unroll") for (int n = 0; n < 4; ++n) {                          \
        bfr[n][0] = *(const bf16x8*)&lds[(BB) + bRow + n * 1024 + c0];         \
        bfr[n][1] = *(const bf16x8*)&lds[(BB) + bRow + n * 1024 + c1];         \
      }                                                                        \
    }                                                                          \
    _Pragma("unroll") for (int dm = 0; dm < 2; ++dm) {                         \
      afr[dm][0] = *(const bf16x8*)&lds[(AB) + aRow + ((Q) * 2 + dm) * 1024 + c0]; \
      afr[dm][1] = *(const bf16x8*)&lds[(AB) + aRow + ((Q) * 2 + dm) * 1024 + c1]; \
    }                                                                          \
    S1;                                                                        \
    S2;                                                                        \
    __builtin_amdgcn_s_barrier();                                              \
    asm volatile("s_waitcnt lgkmcnt(0)" ::: "memory");                         \
    __builtin_amdgcn_sched_barrier(0);                                         \
    __builtin_amdgcn_s_setprio(1);                                             \
    _Pragma("unroll") for (int dm = 0; dm < 2; ++dm)                           \
      _Pragma("unroll") for (int n = 0; n < 4; ++n) {                          \
        acc[(Q) * 2 + dm][n] = __builtin_amdgcn_mfma_f32_16x16x32_bf16(        \
            bfr[n][0], afr[dm][0], acc[(Q) * 2 + dm][n], 0, 0, 0);             \
        acc[(Q) * 2 + dm][n] = __builtin_amdgcn_mfma_f32_16x16x32_bf16(        \
            bfr[n][1], afr[dm][1], acc[(Q) * 2 + dm][n], 0, 0, 0);             \
      }                                                                        \
    __builtin_amdgcn_s_setprio(0);                                             \
    __builtin_amdgcn_sched_barrier(0);                                         \
    asm volatile(VMSTR ::: "memory");                                          \
    __builtin_amdgcn_s_barrier();                                              \
  }

#define ITER8(I, ST, VM4, VM8)                                                 \
  {                                                                            \
    const int t1 = 2 * (I) + 1, t2 = 2 * (I) + 2, t3 = 2 * (I) + 3;            \
    PH8(0, 0, 32768, 1, STA8(1, 0, 0, t1), STA8(1, 0, 1, t1), "")              \
    PH8(1, 0, 32768, 0, STA8(1, 1, 0, t1), STA8(1, 1, 1, t1), "")              \
    PH8(2, 0, 32768, 0, if (ST) STB8(0, 0, 0, t2), if (ST) STB8(0, 0, 1, t2), "") \
    PH8(3, 0, 32768, 0, if (ST) STB8(0, 1, 0, t2), if (ST) STB8(0, 1, 1, t2), VM4) \
    PH8(0, 16384, 49152, 1, if (ST) STA8(0, 0, 0, t2), if (ST) STA8(0, 0, 1, t2), "") \
    PH8(1, 16384, 49152, 0, if (ST) STA8(0, 1, 0, t2), if (ST) STA8(0, 1, 1, t2), "") \
    PH8(2, 16384, 49152, 0, if (ST) STB8(1, 0, 0, t3), if (ST) STB8(1, 0, 1, t3), "") \
    PH8(3, 16384, 49152, 0, if (ST) STB8(1, 1, 0, t3), if (ST) STB8(1, 1, 1, t3), VM8) \
  }

template <int RESID, bool RELU, bool OUTF32>
__global__ __launch_bounds__(512, 2) void gemm8p(
    const uint16_t* __restrict__ A, const uint16_t* __restrict__ Bt,
    const float* __restrict__ bias, const void* __restrict__ resid,
    void* __restrict__ outp, int N, int K, int nbn, int soff) {
  __shared__ __align__(16) uint16_t lds[65536];

  const int nwg = gridDim.x;
  const int s = (blockIdx.x & 7) * (nwg >> 3) + (blockIdx.x >> 3);
  const int bm = s / nbn, bn = s % nbn;
  const int brow = bm << 8, bcol = bn << 8;

  const int tid = threadIdx.x;
  const int w = tid >> 6, lane = tid & 63, l15 = lane & 15, lhi = lane >> 4;
  const int wm = w >> 2, wn = w & 3;

  const int cswz = (tid & 7) ^ ((tid >> 3) & 7);
  const uint32_t aoff32 =
      (uint32_t)(((size_t)(brow + (tid >> 3)) * (size_t)K + cswz * 8) * 2);
  const uint32_t boff32 =
      (uint32_t)(((size_t)(bcol + (tid >> 3)) * (size_t)K + cswz * 8) * 2);
  const char* Ac = (const char*)A;
  const char* Bc = (const char*)Bt;
  const uint32_t kr64b = (uint32_t)(64u * (uint32_t)K * 2u);
  const int wS = w * 512;

  const int c0 = (lhi ^ (l15 & 7)) * 8;
  const int c1 = c0 ^ 32;
  const int aRow = (wm * 128 + l15) * 64;
  const int bRow = (wn * 64 + l15) * 64;

  f32x4 acc[8][4];
  const f32x4 z = {0.f, 0.f, 0.f, 0.f};
#pragma unroll
  for (int m = 0; m < 8; ++m)
#pragma unroll
    for (int n = 0; n < 4; ++n) acc[m][n] = z;

  const int NI = K >> 7;

  STA8(0, 0, 0, 0); STA8(0, 0, 1, 0); STA8(0, 1, 0, 0); STA8(0, 1, 1, 0);
  STB8(0, 0, 0, 0); STB8(0, 0, 1, 0); STB8(0, 1, 0, 0); STB8(0, 1, 1, 0);
  STB8(1, 0, 0, 1); STB8(1, 0, 1, 1); STB8(1, 1, 0, 1); STB8(1, 1, 1, 1);
  asm volatile("s_waitcnt vmcnt(4)" ::: "memory");
  __builtin_amdgcn_s_barrier();
  __builtin_amdgcn_sched_barrier(0);

  {
    bf16x8 afr[2][2], bfr[4][2];
    int i = 0;
    for (; i < NI - 1; ++i)
      ITER8(i, true, "s_waitcnt vmcnt(4)", "s_waitcnt vmcnt(4)")
    ITER8(i, false, "s_waitcnt vmcnt(0)", "")
  }

  // ---- epilogue (swapped layout): lane holds 4 consecutive COLUMNS of one
  // row per (m,n): our_row = brow+wm*128+m*16+l15, our_col = bcol+wn*64+
  // n*16+lhi*4+r. Packed 8B stores/loads; float4 bias; 4x fewer VMEM insts.
#pragma unroll
  for (int n = 0; n < 4; ++n) {
    const int colb = bcol + wn * 64 + n * 16 + lhi * 4;
    const float4 bs4 = *(const float4*)&bias[colb];
#pragma unroll
    for (int m = 0; m < 8; ++m) {
      const int row = brow + wm * 128 + m * 16 + l15;
      float v[4];
#pragma unroll
      for (int r = 0; r < 4; ++r) {
        v[r] = acc[m][n][r] + ((const float*)&bs4)[r];
        if (RELU) v[r] = fmaxf(v[r], 0.f);
      }
      if (RESID == 1) {
        float4 rv = *(const float4*)&((const float*)resid)[(size_t)row * 1024 + colb];
#pragma unroll
        for (int r = 0; r < 4; ++r) v[r] += ((const float*)&rv)[r];
      }
      if (RESID == 2) {
        const size_t rr = ((size_t)(row >> 7) * 256 + soff + (row & 127)) * 1024 + colb;
        float4 rv = *(const float4*)&((const float*)resid)[rr];
#pragma unroll
        for (int r = 0; r < 4; ++r) v[r] += ((const float*)&rv)[r];
      }
      if (RESID == 3) {
        U16x4 rv = *(const U16x4*)&((const uint16_t*)resid)[(size_t)row * 1024 + colb];
        v[0] += bf2f(rv.x); v[1] += bf2f(rv.y); v[2] += bf2f(rv.z); v[3] += bf2f(rv.w);
      }
      if (OUTF32) {
        float4 ov{v[0], v[1], v[2], v[3]};
        *(float4*)&((float*)outp)[(size_t)row * N + colb] = ov;
      } else {
        U16x4 ov{f2bf(v[0]), f2bf(v[1]), f2bf(v[2]), f2bf(v[3])};
        *(U16x4*)&((uint16_t*)outp)[(size_t)row * N + colb] = ov;
      }
    }
  }
}

// ---------------------------------------------------------------------------
// Attention core: one block per (b,h). S=128, dh=64. Q bf16 [t][1024];
// K,V from fused KV buffer [t][2048] (K at col 0, V at col 1024).
// ---------------------------------------------------------------------------
__global__ __launch_bounds__(256) void attn_kern(
    const uint16_t* __restrict__ Q, const uint16_t* __restrict__ KV,
    uint16_t* __restrict__ O) {
  __shared__ uint16_t sm[24576];
  uint16_t* sQ = sm;
  uint16_t* sK = sm + 8192;
  uint16_t* sVt = sm + 16384;
  uint16_t* sP = sm;
  const int bh = blockIdx.x, b = bh >> 4, h = bh & 15;
  const int tid = threadIdx.x, w = tid >> 6, lane = tid & 63, l15 = lane & 15, lhi = lane >> 4;
  const size_t base = (size_t)b * 131072 + h * 64;
  const size_t bkv = (size_t)b * 262144 + h * 64;

  for (int i = 0; i < 4; ++i) {
    const int gidx = i * 256 + tid;
    const int row = gidx >> 3, co = (gidx & 7) * 8;
    *(uint4*)&sQ[row * 64 + co] = *(const uint4*)&Q[base + (size_t)row * 1024 + co];
    *(uint4*)&sK[row * 64 + co] = *(const uint4*)&KV[bkv + (size_t)row * 2048 + co];
  }
  {
    const int r = tid >> 1, cb = (tid & 1) * 32;
    for (int jj = 0; jj < 4; ++jj) {
      uint4 vv = *(const uint4*)&KV[bkv + 1024 + (size_t)r * 2048 + cb + jj * 8];
      const uint16_t* e = (const uint16_t*)&vv;
      for (int j = 0; j < 8; ++j) sVt[(cb + jj * 8 + j) * 128 + r] = e[j];
    }
  }
  __syncthreads();

  f32x4 s[2][8];
  const f32x4 z = {0.f, 0.f, 0.f, 0.f};
  for (int m = 0; m < 2; ++m)
    for (int n = 0; n < 8; ++n) s[m][n] = z;
#pragma unroll
  for (int kk = 0; kk < 2; ++kk) {
    bf16x8 aq[2];
#pragma unroll
    for (int m = 0; m < 2; ++m)
      aq[m] = *(const bf16x8*)&sQ[(w * 32 + m * 16 + l15) * 64 + kk * 32 + lhi * 8];
#pragma unroll
    for (int n = 0; n < 8; ++n) {
      bf16x8 bk = *(const bf16x8*)&sK[(n * 16 + l15) * 64 + kk * 32 + lhi * 8];
#pragma unroll
      for (int m = 0; m < 2; ++m)
        s[m][n] = __builtin_amdgcn_mfma_f32_16x16x32_bf16(aq[m], bk, s[m][n], 0, 0, 0);
    }
  }

  for (int m = 0; m < 2; ++m) {
    float mx[4], sum[4];
#pragma unroll
    for (int r = 0; r < 4; ++r) {
      float v = s[m][0][r];
      for (int n = 1; n < 8; ++n) v = fmaxf(v, s[m][n][r]);
      for (int msk = 1; msk < 16; msk <<= 1) v = fmaxf(v, __shfl_xor(v, msk, 64));
      mx[r] = v;
      sum[r] = 0.f;
    }
    for (int n = 0; n < 8; ++n)
      for (int r = 0; r < 4; ++r) {
        float e = __expf((s[m][n][r] - mx[r]) * 0.125f);
        s[m][n][r] = e;
        sum[r] += e;
      }
#pragma unroll
    for (int r = 0; r < 4; ++r) {
      float t = sum[r];
      for (int msk = 1; msk < 16; msk <<= 1) t += __shfl_xor(t, msk, 64);
      sum[r] = 1.f / t;
    }
    for (int n = 0; n < 8; ++n)
      for (int r = 0; r < 4; ++r) s[m][n][r] *= sum[r];
  }
  __syncthreads();

  for (int m = 0; m < 2; ++m)
    for (int n = 0; n < 8; ++n)
      for (int r = 0; r < 4; ++r)
        sP[(w * 32 + m * 16 + lhi * 4 + r) * 128 + n * 16 + l15] = f2bf(s[m][n][r]);
  __syncthreads();

  f32x4 o[2][4];
  for (int m = 0; m < 2; ++m)
    for (int n = 0; n < 4; ++n) o[m][n] = z;
#pragma unroll
  for (int kk = 0; kk < 4; ++kk) {
    bf16x8 ap[2];
#pragma unroll
    for (int m = 0; m < 2; ++m)
      ap[m] = *(const bf16x8*)&sP[(w * 32 + m * 16 + l15) * 128 + kk * 32 + lhi * 8];
#pragma unroll
    for (int n = 0; n < 4; ++n) {
      bf16x8 bv = *(const bf16x8*)&sVt[(n * 16 + l15) * 128 + kk * 32 + lhi * 8];
#pragma unroll
      for (int m = 0; m < 2; ++m)
        o[m][n] = __builtin_amdgcn_mfma_f32_16x16x32_bf16(ap[m], bv, o[m][n], 0, 0, 0);
    }
  }
  for (int m = 0; m < 2; ++m)
    for (int n = 0; n < 4; ++n)
      for (int r = 0; r < 4; ++r) {
        const int q = w * 32 + m * 16 + lhi * 4 + r, c = n * 16 + l15;
        O[base + (size_t)q * 1024 + c] = f2bf(o[m][n][r]);
      }
}

// ---------------------------------------------------------------------------
// LN2D split. Stats: 512 blocks (4/batch); Apply: 2048 blocks (16/batch).
// ---------------------------------------------------------------------------
__global__ __launch_bounds__(256) void ln_stats(
    const uint16_t* __restrict__ x, float* __restrict__ pstats) {
  const int b = blockIdx.x >> 2, q = blockIdx.x & 3, tid = threadIdx.x;
  const uint16_t* xb = x + (size_t)b * 131072 + q * 32768;
  float s = 0.f, ss = 0.f;
  for (int i = tid; i < 4096; i += 256) {
    U16x8 v = *(const U16x8*)&xb[i * 8];
#pragma unroll
    for (int j = 0; j < 8; ++j) {
      float f = bf2f(v.v[j]);
      s += f;
      ss += f * f;
    }
  }
#pragma unroll
  for (int m = 1; m < 64; m <<= 1) {
    s += __shfl_xor(s, m, 64);
    ss += __shfl_xor(ss, m, 64);
  }
  __shared__ float red[8];
  const int w = tid >> 6;
  if ((tid & 63) == 0) { red[w] = s; red[4 + w] = ss; }
  __syncthreads();
  if (tid == 0) {
    pstats[blockIdx.x * 2] = red[0] + red[1] + red[2] + red[3];
    pstats[blockIdx.x * 2 + 1] = red[4] + red[5] + red[6] + red[7];
  }
}

template <bool FINAL>
__global__ __launch_bounds__(256) void ln_apply(
    const uint16_t* __restrict__ x, const float* __restrict__ g,
    const float* __restrict__ bet, const float* __restrict__ pstats,
    uint16_t* __restrict__ outbf, float* __restrict__ outf) {
  const int b = blockIdx.x >> 4, c = blockIdx.x & 15, tid = threadIdx.x;
  float S = 0.f, SS = 0.f;
#pragma unroll
  for (int k = 0; k < 4; ++k) {
    S += pstats[b * 8 + k * 2];
    SS += pstats[b * 8 + k * 2 + 1];
  }
  const float mu = S * (1.f / 131072.f);
  const float rs = rsqrtf(SS * (1.f / 131072.f) - mu * mu + 1e-5f);
  const size_t xb = (size_t)b * 131072;
#pragma unroll
  for (int j = 0; j < 4; ++j) {
    const int o = c * 8192 + (j * 256 + tid) * 8;
    U16x8 v = *(const U16x8*)&x[xb + o];
    float4 g0 = *(const float4*)&g[o], g1 = *(const float4*)&g[o + 4];
    float4 b0 = *(const float4*)&bet[o], b1 = *(const float4*)&bet[o + 4];
    float r[8];
    r[0] = (bf2f(v.v[0]) - mu) * rs * g0.x + b0.x;
    r[1] = (bf2f(v.v[1]) - mu) * rs * g0.y + b0.y;
    r[2] = (bf2f(v.v[2]) - mu) * rs * g0.z + b0.z;
    r[3] = (bf2f(v.v[3]) - mu) * rs * g0.w + b0.w;
    r[4] = (bf2f(v.v[4]) - mu) * rs * g1.x + b1.x;
    r[5] = (bf2f(v.v[5]) - mu) * rs * g1.y + b1.y;
    r[6] = (bf2f(v.v[6]) - mu) * rs * g1.z + b1.z;
    r[7] = (bf2f(v.v[7]) - mu) * rs * g1.w + b1.w;
    if (FINAL) {
      float4 o0{r[0], r[1], r[2], r[3]}, o1{r[4], r[5], r[6], r[7]};
      float* of = outf + (size_t)b * 262144 + o;
      *(float4*)&of[0] = o0;
      *(float4*)&of[4] = o1;
      if (outbf) {
        U16x8 u;
#pragma unroll
        for (int i = 0; i < 8; ++i) u.v[i] = f2bf(r[i]);
        *(U16x8*)&outbf[xb + o] = u;
      }
    } else {
      U16x8 u;
#pragma unroll
      for (int i = 0; i < 8; ++i) u.v[i] = f2bf(r[i]);
      *(U16x8*)&outbf[xb + o] = u;
    }
  }
}

// ---------------------------------------------------------------------------
extern "C" void kernel_launch(void* const* d_in, const int* in_sizes, int n_in,
                              void* d_out, int out_size, void* d_ws, size_t ws_size,
                              hipStream_t stream) {
  const float* src = (const float*)d_in[0];
  const float* Wq = (const float*)d_in[1];
  const float* bq = (const float*)d_in[2];
  const float* Wk = (const float*)d_in[3];
  const float* bk = (const float*)d_in[4];
  const float* Wv = (const float*)d_in[5];
  const float* bv = (const float*)d_in[6];
  const float* Wo = (const float*)d_in[7];
  const float* bo = (const float*)d_in[8];
  const float* W1 = (const float*)d_in[9];
  const float* b1 = (const float*)d_in[10];
  const float* W2 = (const float*)d_in[11];
  const float* b2 = (const float*)d_in[12];
  const float* g1 = (const float*)d_in[13];
  const float* be1 = (const float*)d_in[14];
  const float* g2 = (const float*)d_in[15];
  const float* be2 = (const float*)d_in[16];
  float* dout = (float*)d_out;
  char* ws = (char*)d_ws;

  const size_t MB = 1024 * 1024;
  uint16_t* wq_t = (uint16_t*)(ws + 0 * MB);
  uint16_t* wkv_t = (uint16_t*)(ws + 2 * MB);  // [2048][1024]: Wk^T then Wv^T
  uint16_t* wv_t = (uint16_t*)(ws + 4 * MB);   // second half of wkv_t
  uint16_t* wo_t = (uint16_t*)(ws + 6 * MB);
  uint16_t* w1_t = (uint16_t*)(ws + 8 * MB);   // [4096][1024]
  uint16_t* w2_t = (uint16_t*)(ws + 16 * MB);  // [1024][4096]
  uint16_t* m1bf = (uint16_t*)(ws + 24 * MB);
  uint16_t* mod2 = (uint16_t*)(ws + 56 * MB);
  uint16_t* QB = (uint16_t*)(ws + 88 * MB);
  uint16_t* KVB = (uint16_t*)(ws + 120 * MB);  // fused [16384][2048]
  uint16_t* ATT = (uint16_t*)(ws + 184 * MB);
  float* bkvp = (float*)(ws + 184 * MB);       // bias staging in ATT head
  uint16_t* Hbf = QB;  // FFN hidden aliases QB..ATT (88..216, all dead)
  uint16_t* mod1 = (uint16_t*)(ws + 216 * MB);
  uint16_t* XAb = (uint16_t*)(ws + 248 * MB);  // bf16 residual stream
  uint16_t* YBF = (uint16_t*)(ws + 280 * MB);  // bf16 LN1 out
  float* pstats = (float*)(ws + 312 * MB);     // 512*2 floats

  dim3 tb(32, 32);
  transpose_cvt<<<dim3(32, 32), tb, 0, stream>>>(Wq, wq_t, 1024, 1024);
  transpose_cvt<<<dim3(32, 32), tb, 0, stream>>>(Wk, wkv_t, 1024, 1024);
  transpose_cvt<<<dim3(32, 32), tb, 0, stream>>>(Wv, wv_t, 1024, 1024);
  transpose_cvt<<<dim3(32, 32), tb, 0, stream>>>(Wo, wo_t, 1024, 1024);
  transpose_cvt<<<dim3(128, 32), tb, 0, stream>>>(W1, w1_t, 1024, 4096);
  transpose_cvt<<<dim3(32, 128), tb, 0, stream>>>(W2, w2_t, 4096, 1024);
  cvt_modal<<<16384, 256, 0, stream>>>(src, mod1, mod2);

  auto phase = [&](const uint16_t* qsrc, const uint16_t* kvsrc, int soff,
                   float* out_f, uint16_t* out_bf) {
    gemm8p<0, false, false><<<256, 512, 0, stream>>>(qsrc, wq_t, bq, nullptr, QB,
                                                     1024, 1024, 4, 0);
    hipMemcpyAsync(bkvp, bk, 4096, hipMemcpyDeviceToDevice, stream);
    hipMemcpyAsync(bkvp + 1024, bv, 4096, hipMemcpyDeviceToDevice, stream);
    gemm8p<0, false, false><<<512, 512, 0, stream>>>(kvsrc, wkv_t, bkvp, nullptr, KVB,
                                                     2048, 1024, 8, 0);
    attn_kern<<<2048, 256, 0, stream>>>(QB, KVB, ATT);
    gemm8p<3, false, false><<<256, 512, 0, stream>>>(ATT, wo_t, bo, qsrc, XAb,
                                                     1024, 1024, 4, 0);
    ln_stats<<<512, 256, 0, stream>>>(XAb, pstats);
    ln_apply<false><<<2048, 256, 0, stream>>>(XAb, g1, be1, pstats, YBF, nullptr);
    gemm8p<0, true, false><<<1024, 512, 0, stream>>>(YBF, w1_t, b1, nullptr, Hbf,
                                                     4096, 1024, 16, 0);
    gemm8p<3, false, false><<<256, 512, 0, stream>>>(Hbf, w2_t, b2, YBF, XAb,
                                                     1024, 4096, 4, 0);
    ln_stats<<<512, 256, 0, stream>>>(XAb, pstats);
    ln_apply<true><<<2048, 256, 0, stream>>>(XAb, g2, be2, pstats, out_bf, out_f);
    (void)soff;
  };

  phase(mod1, mod2, 0, dout, m1bf);
  phase(mod2, m1bf, 128, dout + 131072, nullptr);

  (void)in_sizes; (void)n_in; (void)out_size; (void)ws_size;
}